// Round 4
// baseline (513.229 us; speedup 1.0000x reference)
//
#include <hip/hip_runtime.h>
#include <math.h>

#define H 4096
#define E 64
#define BR 32          // rows per block
#define BK 128         // k-window in floats (512 B contiguous per row-visit)
#define LSTR 132       // padded LDS row stride (floats) -> conflict-free frag reads
#define NT 256         // 4 waves: (mt, kh) = (row-half, k-half)
#define NWIN (H / BK)  // 32

typedef short bf16x8 __attribute__((ext_vector_type(8)));
typedef float f32x4  __attribute__((ext_vector_type(4)));

__device__ __forceinline__ unsigned f2bf_rne_u(float f) {
    unsigned u = __float_as_uint(f);
    return (u + 0x7fffu + ((u >> 16) & 1u)) >> 16;
}

// ---- kernel 1: w fp32 [64][4096] -> w_hi, w_lo bf16 bit patterns ----
__global__ __launch_bounds__(256) void convert_w(const float* __restrict__ w,
                                                 unsigned short* __restrict__ wh,
                                                 unsigned short* __restrict__ wl) {
    const int i = (blockIdx.x * 256 + threadIdx.x) * 4;
    float4 v = *(const float4*)(w + i);
    float vv[4] = {v.x, v.y, v.z, v.w};
    unsigned hh[4], ll[4];
#pragma unroll
    for (int j = 0; j < 4; ++j) {
        hh[j] = f2bf_rne_u(vv[j]);
        float r = vv[j] - __uint_as_float(hh[j] << 16);
        ll[j] = __float_as_uint(r) >> 16;
    }
    ushort4 h, l;
    h.x = (unsigned short)hh[0]; h.y = (unsigned short)hh[1];
    h.z = (unsigned short)hh[2]; h.w = (unsigned short)hh[3];
    l.x = (unsigned short)ll[0]; l.y = (unsigned short)ll[1];
    l.z = (unsigned short)ll[2]; l.w = (unsigned short)ll[3];
    *(ushort4*)(wh + i) = h;
    *(ushort4*)(wl + i) = l;
}

__device__ __forceinline__ void cvt8(const float4 a, const float4 b,
                                     bf16x8& hi, bf16x8& lo) {
    float v[8] = {a.x, a.y, a.z, a.w, b.x, b.y, b.z, b.w};
#pragma unroll
    for (int i = 0; i < 8; ++i) {
        unsigned h = f2bf_rne_u(v[i]);
        float r = v[i] - __uint_as_float(h << 16);
        unsigned l = __float_as_uint(r) >> 16;
        hi[i] = (short)h;
        lo[i] = (short)l;
    }
}

// ---- kernel 2: LDS-staged streaming GEMM + top-2 + softmax ----
// Block: 32 rows x full K. Waves: mt = row-half (16 rows), kh = k-half of each
// window. x staged via double-buffered LDS with 512 B contiguous per-row loads.
__global__ __launch_bounds__(NT, 2) void router_kernel(
    const float* __restrict__ x,
    const unsigned short* __restrict__ wh,
    const unsigned short* __restrict__ wl,
    float* __restrict__ out, int M)
{
    __shared__ __align__(16) float xs[2][BR][LSTR];
    __shared__ __align__(16) f32x4 mrg[8][64];     // kh=1 partials: [mt*4+nt][lane]

    const int t    = threadIdx.x;
    const int lane = t & 63;
    const int wv   = t >> 6;
    const int mt   = wv & 1;          // row half: rows mt*16 .. +16
    const int kh   = wv >> 1;         // k half: steps {2kh, 2kh+1} of each window
    const int col  = lane & 15;
    const int quad = lane >> 4;
    const int m0   = blockIdx.x * BR;

    // ---- staging map: flat 16B-chunk f = t + 256p; row = f>>5, chunk = f&31 ----
    const float* xbase[4];
    float*       lbase[4];
#pragma unroll
    for (int p = 0; p < 4; ++p) {
        const int f   = t + NT * p;
        const int row = f >> 5, ch = f & 31;
        xbase[p] = x + (size_t)(m0 + row) * H + (ch << 2);
        lbase[p] = &xs[0][row][ch << 2];
    }
    const int LBUF = BR * LSTR;       // floats per LDS buffer

    float4 xr[4];
    auto stage_load = [&](int win) {
#pragma unroll
        for (int p = 0; p < 4; ++p)
            xr[p] = *(const float4*)(xbase[p] + (size_t)win * BK);
    };
    auto stage_write = [&](int b) {
#pragma unroll
        for (int p = 0; p < 4; ++p)
            *(float4*)(lbase[p] + b * LBUF) = xr[p];
    };

    const unsigned short* whp = wh + (size_t)col * H + quad * 8;
    const unsigned short* wlp = wl + (size_t)col * H + quad * 8;

    f32x4 acc[4];
#pragma unroll
    for (int nt = 0; nt < 4; ++nt) acc[nt] = (f32x4){0.0f, 0.0f, 0.0f, 0.0f};

    const float* arow = &xs[0][mt * 16 + col][quad * 8];

    stage_load(0);
    stage_write(0);
    __syncthreads();

    for (int win = 0; win < NWIN; ++win) {
        const int buf = win & 1;
        if (win + 1 < NWIN) stage_load(win + 1);   // 4 contiguous-512B loads in flight

#pragma unroll
        for (int si = 0; si < 2; ++si) {
            const int s = kh * 2 + si;             // k32 step within window
            const float* ap = arow + buf * LBUF + s * 32;
            const float4 a0 = *(const float4*)ap;
            const float4 a1 = *(const float4*)(ap + 4);
            bf16x8 ah, al;
            cvt8(a0, a1, ah, al);
            const size_t kg = (size_t)win * BK + s * 32;
#pragma unroll
            for (int nt = 0; nt < 4; ++nt) {
                const uint4 bhv = *(const uint4*)(whp + (size_t)(nt * 16) * H + kg);
                const uint4 blv = *(const uint4*)(wlp + (size_t)(nt * 16) * H + kg);
                const bf16x8 bh = __builtin_bit_cast(bf16x8, bhv);
                const bf16x8 bl = __builtin_bit_cast(bf16x8, blv);
                acc[nt] = __builtin_amdgcn_mfma_f32_16x16x32_bf16(ah, bh, acc[nt], 0, 0, 0);
                acc[nt] = __builtin_amdgcn_mfma_f32_16x16x32_bf16(ah, bl, acc[nt], 0, 0, 0);
                acc[nt] = __builtin_amdgcn_mfma_f32_16x16x32_bf16(al, bh, acc[nt], 0, 0, 0);
            }
        }

        if (win + 1 < NWIN) stage_write(1 - buf);  // waits its own loads post-compute
        __syncthreads();
    }

    // ---- merge the two k-halves ----
    if (kh == 1) {
#pragma unroll
        for (int nt = 0; nt < 4; ++nt)
            mrg[mt * 4 + nt][lane] = acc[nt];
    }
    __syncthreads();
    if (kh == 1) return;
#pragma unroll
    for (int nt = 0; nt < 4; ++nt)
        acc[nt] += mrg[mt * 4 + nt][lane];

    // ---- epilogue: logits + top-2 + softmax (round-3-verified semantics) ----
    float* logits   = out;
    float* idx_out  = out + (size_t)M * E;
    float* prob_out = idx_out + (size_t)M * 2;

    const int mrow0 = m0 + mt * 16 + quad * 4;
#pragma unroll
    for (int r = 0; r < 4; ++r) {
        const int m = mrow0 + r;
#pragma unroll
        for (int nt = 0; nt < 4; ++nt)
            logits[(size_t)m * E + nt * 16 + col] = acc[nt][r];

        float v1 = acc[0][r], v2 = -INFINITY;
        int   i1 = col,       i2 = 0x7fffffff;
#pragma unroll
        for (int nt = 1; nt < 4; ++nt) {
            const float v = acc[nt][r];
            const int   e = nt * 16 + col;
            if (v > v1)      { v2 = v1; i2 = i1; v1 = v; i1 = e; }
            else if (v > v2) { v2 = v;  i2 = e; }
        }
#pragma unroll
        for (int mask = 1; mask < 16; mask <<= 1) {
            const float ov1 = __shfl_xor(v1, mask);
            const float ov2 = __shfl_xor(v2, mask);
            const int   oi1 = __shfl_xor(i1, mask);
            const int   oi2 = __shfl_xor(i2, mask);
            const bool afirst = (v1 > ov1) || (v1 == ov1 && i1 < oi1);
            float nv1, nv2; int ni1, ni2;
            if (afirst) {
                nv1 = v1; ni1 = i1;
                const bool s = (v2 > ov1) || (v2 == ov1 && i2 < oi1);
                nv2 = s ? v2 : ov1; ni2 = s ? i2 : oi1;
            } else {
                nv1 = ov1; ni1 = oi1;
                const bool s = (ov2 > v1) || (ov2 == v1 && oi2 < i1);
                nv2 = s ? ov2 : v1; ni2 = s ? oi2 : i1;
            }
            v1 = nv1; v2 = nv2; i1 = ni1; i2 = ni2;
        }
        if (col == 0) {
            const float e2 = __expf(v2 - v1);   // <= 1
            const float d  = 1.0f + e2;
            *(float2*)(idx_out  + (size_t)m * 2) = make_float2((float)i1, (float)i2);
            *(float2*)(prob_out + (size_t)m * 2) = make_float2(1.0f / d, e2 / d);
        }
    }
}

extern "C" void kernel_launch(void* const* d_in, const int* in_sizes, int n_in,
                              void* d_out, int out_size, void* d_ws, size_t ws_size,
                              hipStream_t stream) {
    const float* x = (const float*)d_in[0];
    const float* w = (const float*)d_in[1];
    unsigned short* wh = (unsigned short*)d_ws;           // 512 KB
    unsigned short* wl = wh + (size_t)E * H;              // 512 KB
    const int M = in_sizes[0] / H;                        // 16384 rows

    hipLaunchKernelGGL(convert_w, dim3((E * H) / 1024), dim3(256), 0, stream,
                       w, wh, wl);
    hipLaunchKernelGGL(router_kernel, dim3(M / BR), dim3(NT), 0, stream,
                       x, wh, wl, (float*)d_out, M);
}

// Round 5
// 495.631 us; speedup vs baseline: 1.0355x; 1.0355x over previous
//
#include <hip/hip_runtime.h>
#include <math.h>

#define H 4096
#define E 64
#define BR 16          // rows per block (one mfma m-tile)
#define NT 256         // 4 waves; each wave owns a k-quarter
#define KQ (H / 4)     // 1024 k per wave
#define BK 32          // k per window (one mfma k-step of the 3-mfma hi/lo group)
#define NWIN (KQ / BK) // 32
#define PF 4           // x prefetch depth (windows)

typedef short bf16x8 __attribute__((ext_vector_type(8)));
typedef float f32x4  __attribute__((ext_vector_type(4)));

__device__ __forceinline__ unsigned f2bf_rne_u(float f) {
    unsigned u = __float_as_uint(f);
    return (u + 0x7fffu + ((u >> 16) & 1u)) >> 16;
}

// ---- kernel 1: w fp32 [64][4096] -> w_hi, w_lo bf16 bit patterns ----
__global__ __launch_bounds__(256) void convert_w(const float* __restrict__ w,
                                                 unsigned short* __restrict__ wh,
                                                 unsigned short* __restrict__ wl) {
    const int i = (blockIdx.x * 256 + threadIdx.x) * 4;
    float4 v = *(const float4*)(w + i);
    float vv[4] = {v.x, v.y, v.z, v.w};
    unsigned hh[4], ll[4];
#pragma unroll
    for (int j = 0; j < 4; ++j) {
        hh[j] = f2bf_rne_u(vv[j]);
        float r = vv[j] - __uint_as_float(hh[j] << 16);
        ll[j] = __float_as_uint(r) >> 16;
    }
    ushort4 h, l;
    h.x = (unsigned short)hh[0]; h.y = (unsigned short)hh[1];
    h.z = (unsigned short)hh[2]; h.w = (unsigned short)hh[3];
    l.x = (unsigned short)ll[0]; l.y = (unsigned short)ll[1];
    l.z = (unsigned short)ll[2]; l.w = (unsigned short)ll[3];
    *(ushort4*)(wh + i) = h;
    *(ushort4*)(wl + i) = l;
}

__device__ __forceinline__ void cvt8(const float4 a, const float4 b,
                                     bf16x8& hi, bf16x8& lo) {
    float v[8] = {a.x, a.y, a.z, a.w, b.x, b.y, b.z, b.w};
#pragma unroll
    for (int i = 0; i < 8; ++i) {
        unsigned h = f2bf_rne_u(v[i]);
        float r = v[i] - __uint_as_float(h << 16);
        unsigned l = __float_as_uint(r) >> 16;
        hi[i] = (short)h;
        lo[i] = (short)l;
    }
}

// ---- kernel 2: barrier-free hi/lo bf16 MFMA GEMM + top-2 + softmax ----
// Block: 16 rows x 64 experts; 4 waves k-split (1024 k each). Grid 1024 ->
// 4 blocks/CU = 16 waves/CU. x prefetched PF=4 windows deep from HBM,
// w-frags 1 window deep from L2. Single end-of-kernel LDS merge.
__global__ __launch_bounds__(NT, 4) void router_kernel(
    const float* __restrict__ x,
    const unsigned short* __restrict__ wh,
    const unsigned short* __restrict__ wl,
    float* __restrict__ out, int M)
{
    __shared__ __align__(16) f32x4 mrg[4][4][64];   // [nt][wave][lane]

    const int t    = threadIdx.x;
    const int lane = t & 63;
    const int wk   = t >> 6;        // k-quarter 0..3
    const int col  = lane & 15;
    const int quad = lane >> 4;
    const int m0   = blockIdx.x * BR;

    const int kbase = wk * KQ + quad * 8;
    const float*          xp  = x  + (size_t)(m0 + col) * H + kbase;
    const unsigned short* whp = wh + (size_t)col * H + kbase;
    const unsigned short* wlp = wl + (size_t)col * H + kbase;

    f32x4 acc[4];
#pragma unroll
    for (int nt = 0; nt < 4; ++nt) acc[nt] = (f32x4){0.0f, 0.0f, 0.0f, 0.0f};

    float4 xr[PF][2];
    uint4  brh[4], brl[4];

    // ---- preload: x windows 0..PF-1, b window 0 ----
#pragma unroll
    for (int p = 0; p < PF; ++p) {
        xr[p][0] = *(const float4*)(xp + p * BK);
        xr[p][1] = *(const float4*)(xp + p * BK + 4);
    }
#pragma unroll
    for (int nt = 0; nt < 4; ++nt) {
        brh[nt] = *(const uint4*)(whp + (size_t)(nt * 16) * H);
        brl[nt] = *(const uint4*)(wlp + (size_t)(nt * 16) * H);
    }

#pragma unroll 4
    for (int win = 0; win < NWIN; ++win) {
        const int slot = win & (PF - 1);

        // snapshot current frags
        bf16x8 ah, al;
        cvt8(xr[slot][0], xr[slot][1], ah, al);
        bf16x8 bh[4], bl[4];
#pragma unroll
        for (int nt = 0; nt < 4; ++nt) {
            bh[nt] = __builtin_bit_cast(bf16x8, brh[nt]);
            bl[nt] = __builtin_bit_cast(bf16x8, brl[nt]);
        }

        // issue prefetches (x: PF ahead, b: 1 ahead)
        if (win + PF < NWIN) {
            xr[slot][0] = *(const float4*)(xp + (win + PF) * BK);
            xr[slot][1] = *(const float4*)(xp + (win + PF) * BK + 4);
        }
        if (win + 1 < NWIN) {
            const int k = (win + 1) * BK;
#pragma unroll
            for (int nt = 0; nt < 4; ++nt) {
                brh[nt] = *(const uint4*)(whp + (size_t)(nt * 16) * H + k);
                brl[nt] = *(const uint4*)(wlp + (size_t)(nt * 16) * H + k);
            }
        }

        // compute
#pragma unroll
        for (int nt = 0; nt < 4; ++nt) {
            acc[nt] = __builtin_amdgcn_mfma_f32_16x16x32_bf16(ah, bh[nt], acc[nt], 0, 0, 0);
            acc[nt] = __builtin_amdgcn_mfma_f32_16x16x32_bf16(ah, bl[nt], acc[nt], 0, 0, 0);
            acc[nt] = __builtin_amdgcn_mfma_f32_16x16x32_bf16(al, bh[nt], acc[nt], 0, 0, 0);
        }
    }

    // ---- cross-wave k-merge via LDS ----
#pragma unroll
    for (int nt = 0; nt < 4; ++nt)
        mrg[nt][wk][lane] = acc[nt];
    __syncthreads();
    if (wk != 0) return;

#pragma unroll
    for (int nt = 0; nt < 4; ++nt)
#pragma unroll
        for (int w = 1; w < 4; ++w)
            acc[nt] += mrg[nt][w][lane];

    // ---- epilogue: logits + top-2 + softmax (r3-verified semantics) ----
    float* logits   = out;
    float* idx_out  = out + (size_t)M * E;
    float* prob_out = idx_out + (size_t)M * 2;

    const int mrow0 = m0 + quad * 4;
#pragma unroll
    for (int r = 0; r < 4; ++r) {
        const int m = mrow0 + r;
#pragma unroll
        for (int nt = 0; nt < 4; ++nt)
            logits[(size_t)m * E + nt * 16 + col] = acc[nt][r];

        float v1 = acc[0][r], v2 = -INFINITY;
        int   i1 = col,       i2 = 0x7fffffff;
#pragma unroll
        for (int nt = 1; nt < 4; ++nt) {
            const float v = acc[nt][r];
            const int   e = nt * 16 + col;
            if (v > v1)      { v2 = v1; i2 = i1; v1 = v; i1 = e; }
            else if (v > v2) { v2 = v;  i2 = e; }
        }
#pragma unroll
        for (int mask = 1; mask < 16; mask <<= 1) {
            const float ov1 = __shfl_xor(v1, mask);
            const float ov2 = __shfl_xor(v2, mask);
            const int   oi1 = __shfl_xor(i1, mask);
            const int   oi2 = __shfl_xor(i2, mask);
            const bool afirst = (v1 > ov1) || (v1 == ov1 && i1 < oi1);
            float nv1, nv2; int ni1, ni2;
            if (afirst) {
                nv1 = v1; ni1 = i1;
                const bool s = (v2 > ov1) || (v2 == ov1 && i2 < oi1);
                nv2 = s ? v2 : ov1; ni2 = s ? i2 : oi1;
            } else {
                nv1 = ov1; ni1 = oi1;
                const bool s = (ov2 > v1) || (ov2 == v1 && oi2 < i1);
                nv2 = s ? ov2 : v1; ni2 = s ? oi2 : i1;
            }
            v1 = nv1; v2 = nv2; i1 = ni1; i2 = ni2;
        }
        if (col == 0) {
            const float e2 = __expf(v2 - v1);   // <= 1
            const float d  = 1.0f + e2;
            *(float2*)(idx_out  + (size_t)m * 2) = make_float2((float)i1, (float)i2);
            *(float2*)(prob_out + (size_t)m * 2) = make_float2(1.0f / d, e2 / d);
        }
    }
}

extern "C" void kernel_launch(void* const* d_in, const int* in_sizes, int n_in,
                              void* d_out, int out_size, void* d_ws, size_t ws_size,
                              hipStream_t stream) {
    const float* x = (const float*)d_in[0];
    const float* w = (const float*)d_in[1];
    unsigned short* wh = (unsigned short*)d_ws;           // 512 KB
    unsigned short* wl = wh + (size_t)E * H;              // 512 KB
    const int M = in_sizes[0] / H;                        // 16384 rows

    hipLaunchKernelGGL(convert_w, dim3((E * H) / 1024), dim3(256), 0, stream,
                       w, wh, wl);
    hipLaunchKernelGGL(router_kernel, dim3(M / BR), dim3(NT), 0, stream,
                       x, wh, wl, (float*)d_out, M);
}